// Round 3
// baseline (385.807 us; speedup 1.0000x reference)
//
#include <hip/hip_runtime.h>
#include <stdint.h>

// Problem constants (B=64, P=24564, 21 classes)
#define NC 21
#define BATCH 64
#define PRI 24564
#define NROWS (BATCH * PRI)   // 1,572,096
#define SLABS 32              // slabs per batch row
#define SLABR 768             // rows per slab (last slab: 756 valid)
#define GBLK (BATCH * SLABS)  // 2048 grid-wide blocks for k_main
#define CHUNK 96              // rows per thread in ordered (chunked) scans

// float4 with 4-byte alignment (conf rows are 84B-strided, only dword-aligned)
typedef float f4a4 __attribute__((ext_vector_type(4), aligned(4)));

__device__ __forceinline__ float sl1f(float p, float t) {
    float d = fabsf(p - t);
    return d < 1.0f ? 0.5f * d * d : d - 0.5f;
}

// monotonic float -> uint key map (order-preserving)
__device__ __forceinline__ unsigned int f2k(float v) {
    unsigned int u = __float_as_uint(v);
    return (u & 0x80000000u) ? ~u : (u | 0x80000000u);
}

// selection key from packed (ce, hlce|posbit); pos -> f2k(0.0) = 0x80000000
__device__ __forceinline__ unsigned int chkey(float2 ch) {
    unsigned hb = __float_as_uint(ch.y);
    return (hb & 0x80000000u) ? 0x80000000u : f2k(ch.x);
}

// 256-thread block reduce (4 waves of 64). Valid on tid==0 only.
__device__ __forceinline__ double blockReduce(double v, double* sred) {
    #pragma unroll
    for (int off = 32; off > 0; off >>= 1)
        v += __shfl_down(v, off, 64);
    const int wid = threadIdx.x >> 6, lane = threadIdx.x & 63;
    __syncthreads();
    if (lane == 0) sred[wid] = v;
    __syncthreads();
    double r = 0.0;
    if (threadIdx.x == 0) r = sred[0] + sred[1] + sred[2] + sred[3];
    return r;
}

// Pass 1 (verbatim round-1 verified): per-row conf CE + has_lp CE -> ws_ch;
// smooth-L1 partials; num_pos; round-1 radix histogram (top 12 key bits).
__global__ __launch_bounds__(256, 4) void k_main(
    const float* __restrict__ loc_data, const float* __restrict__ conf_data,
    const float* __restrict__ has_lp_data, const float* __restrict__ size_lp_data,
    const float* __restrict__ offset_data, const float* __restrict__ loc_t,
    const int* __restrict__ conf_t, const int* __restrict__ has_lp_t,
    const float* __restrict__ size_lp_t, const float* __restrict__ offset_t,
    float2* __restrict__ ws_ch, int* __restrict__ numpos, double* __restrict__ part,
    int* __restrict__ ghist1)
{
    __shared__ int hist[4096];
    __shared__ double sred[4];
    const int tid = threadIdx.x;
    const int b = blockIdx.x >> 5, s = blockIdx.x & 31;
    for (int k = tid; k < 4096; k += 256) hist[k] = 0;
    __syncthreads();

    int pr[3]; bool vld[3];
    #pragma unroll
    for (int i = 0; i < 3; ++i) {
        int p = s * SLABR + i * 256 + tid;
        vld[i] = p < PRI;
        pr[i] = vld[i] ? p : PRI - 1;   // clamp: loads unconditional, safe
    }
    const unsigned rb = (unsigned)b * PRI;

    // ---------- phase A: 21-class conf CE ----------
    int ct[3];
    #pragma unroll
    for (int i = 0; i < 3; ++i) ct[i] = conf_t[rb + pr[i]];
    f4a4 cw[3][5]; float c20[3], gg[3];
    #pragma unroll
    for (int i = 0; i < 3; ++i) {
        const float* crow = conf_data + (long)(rb + pr[i]) * NC;
        #pragma unroll
        for (int j = 0; j < 5; ++j) cw[i][j] = ((const f4a4*)crow)[j];
        c20[i] = crow[20];
        gg[i] = crow[ct[i]];
    }
    float ce[3];
    #pragma unroll
    for (int i = 0; i < 3; ++i) {
        float m = c20[i];
        #pragma unroll
        for (int j = 0; j < 5; ++j)
            m = fmaxf(m, fmaxf(fmaxf(cw[i][j].x, cw[i][j].y), fmaxf(cw[i][j].z, cw[i][j].w)));
        float sum = __expf(c20[i] - m);
        #pragma unroll
        for (int j = 0; j < 5; ++j)
            sum += __expf(cw[i][j].x - m) + __expf(cw[i][j].y - m)
                 + __expf(cw[i][j].z - m) + __expf(cw[i][j].w - m);
        ce[i] = m + __logf(sum) - gg[i];
    }
    // histogram only nonzero-key rows (negatives with ce != +0): no contention
    #pragma unroll
    for (int i = 0; i < 3; ++i) {
        if (vld[i] && ct[i] <= 0) {
            unsigned key = f2k(ce[i]);
            if (key != 0x80000000u) atomicAdd(&hist[key >> 20], 1);
        }
    }

    // ---------- phase B: smooth-L1 + has_lp CE ----------
    int hl[3]; float4 lp[3], lt[3]; float2 sp2[3], st2[3], op2[3], ot2[3], hh[3];
    #pragma unroll
    for (int i = 0; i < 3; ++i) {
        const unsigned r = rb + pr[i];
        hl[i] = has_lp_t[r];
        lp[i] = ((const float4*)loc_data)[r];
        lt[i] = ((const float4*)loc_t)[r];
        sp2[i] = ((const float2*)size_lp_data)[r];
        st2[i] = ((const float2*)size_lp_t)[r];
        op2[i] = ((const float2*)offset_data)[r];
        ot2[i] = ((const float2*)offset_t)[r];
        hh[i] = ((const float2*)has_lp_data)[r];
    }
    double aL = 0.0, aS = 0.0, aO = 0.0;
    int myp = 0;
    #pragma unroll
    for (int i = 0; i < 3; ++i) {
        const bool pos = ct[i] > 0;
        float ll = sl1f(lp[i].x, lt[i].x) + sl1f(lp[i].y, lt[i].y)
                 + sl1f(lp[i].z, lt[i].z) + sl1f(lp[i].w, lt[i].w);
        float ls = sl1f(sp2[i].x, st2[i].x) + sl1f(sp2[i].y, st2[i].y);
        float lo = sl1f(op2[i].x, ot2[i].x) + sl1f(op2[i].y, ot2[i].y);
        const float pf = (vld[i] && pos) ? 1.f : 0.f;
        const float hf = (hl[i] != 0) ? 1.f : 0.f;
        aL += (double)(pf * ll);
        aS += (double)(pf * hf * ls);
        aO += (double)(pf * hf * lo);
        float hm = fmaxf(hh[i].x, hh[i].y);
        float hs = __expf(hh[i].x - hm) + __expf(hh[i].y - hm);
        float hlce = fmaxf(hm + __logf(hs) - (hl[i] != 0 ? hh[i].y : hh[i].x), 0.0f);
        unsigned hb = __float_as_uint(hlce) | (pos ? 0x80000000u : 0u);
        if (vld[i]) ws_ch[rb + pr[i]] = make_float2(ce[i], __uint_as_float(hb));
        myp += (vld[i] && pos) ? 1 : 0;
    }

    double v;
    v = blockReduce(aL, sred); if (tid == 0) part[0 * GBLK + blockIdx.x] = v;
    v = blockReduce(aS, sred); if (tid == 0) part[1 * GBLK + blockIdx.x] = v;
    v = blockReduce(aO, sred); if (tid == 0) part[2 * GBLK + blockIdx.x] = v;
    v = blockReduce((double)myp, sred);
    if (tid == 0 && v > 0.0) atomicAdd(&numpos[b], (int)(v + 0.5));

    __syncthreads();
    for (int k = tid; k < 4096; k += 256) {
        int h = hist[k];
        if (h) atomicAdd(&ghist1[(b << 12) + k], h);
    }
}

// Per-batch selection pipeline, one block per batch. Replaces pick0 + 2x(hist+pick)
// + sel2 + cut (6 dispatches) with block-local phases: refinement histograms live
// in LDS (no global ghist2/3), selection/cut are 3 short scans of the batch's
// 196 KB ws_ch slice (L2-resident after k_main).
__global__ __launch_bounds__(256) void k_batch(
    const float2* __restrict__ ws_ch, const int* __restrict__ ghist1,
    const int* __restrict__ numpos, double* __restrict__ lossCH)
{
    const int b = blockIdx.x, tid = threadIdx.x;
    __shared__ int sct[256];
    __shared__ int shist[1024];
    __shared__ double sred[4];
    __shared__ unsigned s_dig;
    __shared__ int s_rem;
    __shared__ int s_cut;

    const float2* row = ws_ch + (unsigned)b * PRI;

    // ---------------- round-0 digit pick + mode decision (12 top bits) --------
    int K = 3 * numpos[b]; if (K > PRI - 1) K = PRI - 1;
    int h[16];
    {
        const int* g = ghist1 + (b << 12) + tid * 16;
        int ctn = 0;
        #pragma unroll
        for (int j = 0; j < 16; ++j) { h[j] = g[j]; ctn += h[j]; }
        sct[tid] = ctn;
    }
    __syncthreads();
    #pragma unroll
    for (int off = 1; off < 256; off <<= 1) {
        int v = (tid + off < 256) ? sct[tid + off] : 0;
        __syncthreads();
        sct[tid] += v;
        __syncthreads();
    }
    const int M = sct[0];

    unsigned T; int need;
    if (K <= 0) {
        T = 0xFFFFFFFFu; need = 0;          // select positives only (none)
    } else if (K > M) {
        T = 0x80000000u; need = K - M;      // threshold in zero-key population
    } else {
        // digit pick on 4096 bins
        const int Safter = (tid < 255) ? sct[tid + 1] : 0;
        int cum = Safter;
        #pragma unroll
        for (int j = 15; j >= 0; --j) {
            int c2 = cum + h[j];
            if (c2 >= K && cum < K) { s_dig = (unsigned)(tid * 16 + j); s_rem = K - cum; }
            cum = c2;
        }
        __syncthreads();
        unsigned pref = s_dig; int rem = s_rem;

        // ---- refine round 1: LDS 1024-bin hist on bits 19..10, key>>20==pref --
        for (int k = tid; k < 1024; k += 256) shist[k] = 0;
        __syncthreads();
        for (int p = tid; p < PRI; p += 256) {
            unsigned key = chkey(row[p]);
            if (key != 0x80000000u && (key >> 20) == pref)
                atomicAdd(&shist[(key >> 10) & 1023], 1);
        }
        __syncthreads();
        {
            int h4[4]; int c4 = 0;
            #pragma unroll
            for (int j = 0; j < 4; ++j) { h4[j] = shist[tid * 4 + j]; c4 += h4[j]; }
            __syncthreads();                 // shist reads done before sct reuse is fine; guard sct
            sct[tid] = c4;
            __syncthreads();
            #pragma unroll
            for (int off = 1; off < 256; off <<= 1) {
                int v = (tid + off < 256) ? sct[tid + off] : 0;
                __syncthreads();
                sct[tid] += v;
                __syncthreads();
            }
            const int Sa = (tid < 255) ? sct[tid + 1] : 0;
            int cum2 = Sa;
            #pragma unroll
            for (int j = 3; j >= 0; --j) {
                int c2 = cum2 + h4[j];
                if (c2 >= rem && cum2 < rem) { s_dig = (unsigned)(tid * 4 + j); s_rem = rem - cum2; }
                cum2 = c2;
            }
            __syncthreads();
        }
        pref = (pref << 10) | s_dig; rem = s_rem;
        __syncthreads();

        // ---- refine round 2: LDS 1024-bin hist on low 10 bits, key>>10==pref --
        for (int k = tid; k < 1024; k += 256) shist[k] = 0;
        __syncthreads();
        for (int p = tid; p < PRI; p += 256) {
            unsigned key = chkey(row[p]);
            if (key != 0x80000000u && (key >> 10) == pref)
                atomicAdd(&shist[key & 1023], 1);
        }
        __syncthreads();
        {
            int h4[4]; int c4 = 0;
            #pragma unroll
            for (int j = 0; j < 4; ++j) { h4[j] = shist[tid * 4 + j]; c4 += h4[j]; }
            __syncthreads();
            sct[tid] = c4;
            __syncthreads();
            #pragma unroll
            for (int off = 1; off < 256; off <<= 1) {
                int v = (tid + off < 256) ? sct[tid + off] : 0;
                __syncthreads();
                sct[tid] += v;
                __syncthreads();
            }
            const int Sa = (tid < 255) ? sct[tid + 1] : 0;
            int cum2 = Sa;
            #pragma unroll
            for (int j = 3; j >= 0; --j) {
                int c2 = cum2 + h4[j];
                if (c2 >= rem && cum2 < rem) { s_dig = (unsigned)(tid * 4 + j); s_rem = rem - cum2; }
                cum2 = c2;
            }
            __syncthreads();
        }
        T = (pref << 10) | s_dig; need = s_rem;
        __syncthreads();
    }

    // ---------------- scan A: selected-core sums (pos || key > T), coalesced --
    double aC = 0.0, aH = 0.0;
    for (int p = tid; p < PRI; p += 256) {
        float2 ch = row[p];
        unsigned hb = __float_as_uint(ch.y);
        const bool pos = (hb >> 31) != 0;
        const unsigned key = pos ? 0x80000000u : f2k(ch.x);
        const float hlv = __uint_as_float(hb & 0x7fffffffu);
        if (pos || key > T) { aC += (double)ch.x; aH += (double)hlv; }
    }

    // ---------------- scan B: ordered tie localization (chunk per thread) -----
    // Reference tie-break: stable argsort -> among key==T ties the first `need`
    // in original index order are selected. Find cutoff = index of need-th tie.
    if (tid == 0) s_cut = -1;
    __syncthreads();
    const int c0 = tid * CHUNK;
    const int c1 = (c0 + CHUNK < PRI) ? c0 + CHUNK : PRI;
    int tcnt = 0;
    if (need > 0) {
        for (int p = c0; p < c1; ++p) tcnt += (chkey(row[p]) == T) ? 1 : 0;
    }
    sct[tid] = tcnt;
    __syncthreads();
    #pragma unroll
    for (int off = 1; off < 256; off <<= 1) {   // ascending inclusive prefix sum
        int v = (tid >= off) ? sct[tid - off] : 0;
        __syncthreads();
        sct[tid] += v;
        __syncthreads();
    }
    if (need > 0) {
        const int incl = sct[tid], excl = incl - tcnt;
        if (excl < need && need <= incl) {       // my chunk holds the need-th tie
            int want = need - excl, c = 0;
            for (int p = c0; p < c1; ++p) {
                if (chkey(row[p]) == T) { ++c; if (c == want) { s_cut = p; break; } }
            }
        }
    }
    __syncthreads();
    const int cutoff = s_cut;

    // ---------------- scan C: negative ties with p <= cutoff ------------------
    double tCn = 0.0, tHn = 0.0;
    for (int p = tid; p <= cutoff; p += 256) {   // cutoff < PRI; -1 -> skip
        float2 ch = row[p];
        unsigned hb = __float_as_uint(ch.y);
        const bool pos = (hb >> 31) != 0;
        if (!pos) {
            const unsigned key = f2k(ch.x);
            if (key == T) {
                tCn += (double)ch.x;
                tHn += (double)__uint_as_float(hb & 0x7fffffffu);
            }
        }
    }

    double totC = blockReduce(aC + tCn, sred);
    double totH = blockReduce(aH + tHn, sred);
    if (tid == 0) { lossCH[b] = totC; lossCH[64 + b] = totH; }
}

// Sum partials, divide by N, emit 5 outputs.
__global__ __launch_bounds__(256) void k_final(
    const double* __restrict__ part, const int* __restrict__ numpos,
    const double* __restrict__ lossCH, float* __restrict__ out)
{
    __shared__ double sred[4];
    const int tid = threadIdx.x;
    double s[3];
    #pragma unroll
    for (int k = 0; k < 3; ++k) {
        double a = 0.0;
        for (int t = tid; t < GBLK; t += 256) a += part[k * GBLK + t];
        s[k] = blockReduce(a, sred);
    }
    double lc = (tid < BATCH) ? lossCH[tid] : 0.0;
    lc = blockReduce(lc, sred);
    double lh = (tid < BATCH) ? lossCH[64 + tid] : 0.0;
    lh = blockReduce(lh, sred);
    double n = (tid < BATCH) ? (double)numpos[tid] : 0.0;
    n = blockReduce(n, sred);
    if (tid == 0) {
        out[0] = (float)(s[0] / n);   // loss_l
        out[1] = (float)(lc / n);     // loss_c
        out[2] = (float)(s[1] / n);   // loss_size_lp
        out[3] = (float)(s[2] / n);   // loss_offset
        out[4] = (float)(lh / n);     // loss_has_lp
    }
}

extern "C" void kernel_launch(void* const* d_in, const int* in_sizes, int n_in,
                              void* d_out, int out_size, void* d_ws, size_t ws_size,
                              hipStream_t stream)
{
    const float* loc_data     = (const float*)d_in[0];
    const float* conf_data    = (const float*)d_in[1];
    const float* has_lp_data  = (const float*)d_in[2];
    const float* size_lp_data = (const float*)d_in[3];
    const float* offset_data  = (const float*)d_in[4];
    const float* loc_t        = (const float*)d_in[5];
    const int*   conf_t       = (const int*)d_in[6];
    const int*   has_lp_t     = (const int*)d_in[7];
    const float* size_lp_t    = (const float*)d_in[8];
    const float* offset_t     = (const float*)d_in[9];
    float* out = (float*)d_out;

    char* ws = (char*)d_ws;
    int* numpos      = (int*)(ws + 0);           // 64 int
    double* part     = (double*)(ws + 16384);    // 3*2048 doubles (48 KB)
    double* lossCH   = (double*)(ws + 131072);   // 128 doubles
    int* ghist1      = (int*)(ws + 132096);      // 64*4096 int (1 MB)
    float2* ws_ch    = (float2*)(ws + 1704960);  // NROWS float2 (~12.6 MB)

    hipMemsetAsync(ws, 0, 256, stream);                  // numpos
    hipMemsetAsync(ws + 132096, 0, 1048576, stream);     // ghist1

    k_main<<<GBLK, 256, 0, stream>>>(loc_data, conf_data, has_lp_data, size_lp_data,
                                     offset_data, loc_t, conf_t, has_lp_t,
                                     size_lp_t, offset_t, ws_ch, numpos, part, ghist1);
    k_batch<<<BATCH, 256, 0, stream>>>(ws_ch, ghist1, numpos, lossCH);
    k_final<<<1, 256, 0, stream>>>(part, numpos, lossCH, out);
}